// Round 9
// baseline (113.007 us; speedup 1.0000x reference)
//
#include <hip/hip_runtime.h>

typedef _Float16 f16;
typedef _Float16 f16x8 __attribute__((ext_vector_type(8)));
typedef _Float16 f16x4 __attribute__((ext_vector_type(4)));
typedef float f32x4 __attribute__((ext_vector_type(4)));

// ---------------- d_ws layout ----------------
// [0, 262144) : f16 weight images, per-lane MFMA A-fragment order:
//   elem (T,ks,lane,j): value = W[k = ks*32+(lane>>4)*8+j][ch = T*16+(lane&15)]
//   at imgbase + ((T*nks + ks)*64 + lane)*16 + j*2
//   L1..L7 (128x128, nks=4, 8 T): i*32768, i=0..6   (L5 uses dW5 rows 67..194)
//   C0h    (128x64,  nks=4, 4 T): 229376, 16384 B   (cW0 rows 0..127)
//   C1     (64x64,   nks=2, 4 T): 245760, 8192 B
//   C2     (64x64,   nks=2, 4 T): 253952, 8192 B
// [262144, +10240) : fp32 params block (R1/R4/R6 layout):
//   0 b0f[128] | 128 W0p[3][128] | 512 b5f[128] | 640 W5p[3][128]
//   1024 db1 1152 db2 1280 db3 1408 db4 1536 db6 1664 db7 (x128)
//   1792 cb0[64] | 1856 cWv[3][64] | 2048 cb1[64] | 2112 cb2[64]
//   2176 sW[128] | 2304 sb | 2305 rW[64][3] | 2497 rb[3]
#define WS_PARAMS 262144

// ---------------- LDS layout (bytes) — kept IDENTICAL to passing R6 ----------
// (W0/W1 regions are now unused; kept so the build/occupancy env matches R6.)
#define LDS_ACT   0
#define LDS_W0    65536
#define LDS_W1    98304
#define LDS_PRM   131072
#define LDS_POS   141312
#define LDS_VIEW  144384
#define LDS_SIG   144408
#define LDS_SIZE  145440

__device__ __forceinline__ int swz(int row, int byteInRow) {
  return byteInRow ^ ((row & 7) << 4);
}

struct Ptrs { const float* p[29]; };

// ---------------------------------------------------------------------------
// Prepass: params block verbatim from validated R4/R6; weight-fragment
// packing verbatim from R2 (first-call validated at absmax 2.44e-4).
// ---------------------------------------------------------------------------
__global__ void nerf_prep(Ptrs ptrs, char* __restrict__ ws) {
  const int t = threadIdx.x;
  if (blockIdx.x == 0) {
    float* P = (float*)(ws + WS_PARAMS);
    const float* cond = ptrs.p[1];
    const float* dW0 = ptrs.p[3];  const float* db0 = ptrs.p[4];
    const float* dW5 = ptrs.p[13]; const float* db5 = ptrs.p[14];
    if (t < 128) {
      float a0 = db0[t], a5 = db5[t];
      for (int k = 0; k < 64; ++k) {
        const float c = cond[k];
        a0 += c * dW0[(3 + k) * 128 + t];
        a5 += c * dW5[(3 + k) * 128 + t];
      }
      P[t] = a0;          // b0f
      P[512 + t] = a5;    // b5f
      for (int k = 0; k < 3; ++k) {
        P[128 + k * 128 + t] = dW0[k * 128 + t];   // W0p
        P[640 + k * 128 + t] = dW5[k * 128 + t];   // W5p
      }
      P[1024 + t] = ptrs.p[6][t];    // db1
      P[1152 + t] = ptrs.p[8][t];    // db2
      P[1280 + t] = ptrs.p[10][t];   // db3
      P[1408 + t] = ptrs.p[12][t];   // db4
      P[1536 + t] = ptrs.p[16][t];   // db6
      P[1664 + t] = ptrs.p[18][t];   // db7
      P[2176 + t] = ptrs.p[19][t];   // sW
    }
    if (t < 64) {
      P[1792 + t] = ptrs.p[22][t];   // cb0
      for (int k = 0; k < 3; ++k)    // cWv = cW0 rows 128..130
        P[1856 + k * 64 + t] = ptrs.p[21][(128 + k) * 64 + t];
      P[2048 + t] = ptrs.p[24][t];   // cb1
      P[2112 + t] = ptrs.p[26][t];   // cb2
    }
    if (t < 192) P[2305 + t] = ptrs.p[27][t];  // rW [64][3]
    if (t == 0) {
      P[2304] = ptrs.p[20][0];                 // sb
      P[2497] = ptrs.p[28][0];
      P[2498] = ptrs.p[28][1];
      P[2499] = ptrs.p[28][2];                 // rb
    }
    return;
  }
  // 131072 f16 weight-fragment elements across blocks 1..512 (R2 formulas)
  const int e = (blockIdx.x - 1) * 256 + t;
  float v; int dst;
  if (e < 114688) {                       // L1..L7
    const int img = e >> 14, o = e & 16383;
    const int j = o & 7, lane = (o >> 3) & 63, ks = (o >> 9) & 3, T = o >> 11;
    const int k = ks * 32 + ((lane >> 4) << 3) + j, ch = T * 16 + (lane & 15);
    v = ptrs.p[5 + 2 * img][(k + (img == 4 ? 67 : 0)) * 128 + ch];
    dst = img * 32768 + (((T * 4 + ks) * 64 + lane) << 4) + (j << 1);
  } else if (e < 122880) {                // C0h
    const int o = e - 114688;
    const int j = o & 7, lane = (o >> 3) & 63, ks = (o >> 9) & 3, T = o >> 11;
    const int k = ks * 32 + ((lane >> 4) << 3) + j, ch = T * 16 + (lane & 15);
    v = ptrs.p[21][k * 64 + ch];
    dst = 229376 + (((T * 4 + ks) * 64 + lane) << 4) + (j << 1);
  } else if (e < 126976) {                // C1
    const int o = e - 122880;
    const int j = o & 7, lane = (o >> 3) & 63, ks = (o >> 9) & 1, T = o >> 10;
    const int k = ks * 32 + ((lane >> 4) << 3) + j, ch = T * 16 + (lane & 15);
    v = ptrs.p[23][k * 64 + ch];
    dst = 245760 + (((T * 2 + ks) * 64 + lane) << 4) + (j << 1);
  } else {                                // C2
    const int o = e - 126976;
    const int j = o & 7, lane = (o >> 3) & 63, ks = (o >> 9) & 1, T = o >> 10;
    const int k = ks * 32 + ((lane >> 4) << 3) + j, ch = T * 16 + (lane & 15);
    v = ptrs.p[25][k * 64 + ch];
    dst = 253952 + (((T * 2 + ks) * 64 + lane) << 4) + (j << 1);
  }
  *(f16*)(ws + dst) = (f16)v;
}

// ---------------------------------------------------------------------------
// layerF: identical to validated R6 except the A-fragment source — per-ks
// global_load_dwordx4 from the fragment-ordered image (L1-resident) instead
// of ds_read from a DMA-staged LDS buffer. B from LDS act; C row=och, col=pt.
// INIT: 0 = bias only, 1 = bias + pos*W5p, 2 = bias + view*cWv
// ---------------------------------------------------------------------------
template<int K, int N, int INIT>
__device__ __forceinline__ void layerF(char* L, int biasOff,
                                       const char* __restrict__ img,
                                       int pg, int cg, int lane) {
  const float* P = (const float*)(L + LDS_PRM);
  const int col = lane & 15, kg = lane >> 4;
  constexpr int nCT = (N == 128) ? 4 : 2;
  constexpr int NKS = K / 32;
  const int ochQ = kg * 4;
  f32x4 acc[4][nCT];
#pragma unroll
  for (int ct = 0; ct < nCT; ++ct) {
    const int ochB = (cg * nCT + ct) * 16 + ochQ;
    const f32x4 bq = *(const f32x4*)(P + biasOff + ochB);
    f32x4 w0q, w1q, w2q;
    if (INIT == 1) {
      w0q = *(const f32x4*)(P + 640 + ochB);
      w1q = *(const f32x4*)(P + 768 + ochB);
      w2q = *(const f32x4*)(P + 896 + ochB);
    } else if (INIT == 2) {
      w0q = *(const f32x4*)(P + 1856 + ochB);
      w1q = *(const f32x4*)(P + 1920 + ochB);
      w2q = *(const f32x4*)(P + 1984 + ochB);
    }
#pragma unroll
    for (int ptc = 0; ptc < 4; ++ptc) {
      f32x4 v = bq;
      if (INIT != 0) {
        const int pt = pg * 64 + ptc * 16 + col;
        float p0, p1, p2;
        if (INIT == 1) {
          const float* pp = (const float*)(L + LDS_POS) + pt * 3;
          p0 = pp[0]; p1 = pp[1]; p2 = pp[2];
        } else {
          const float* vv = (const float*)(L + LDS_VIEW) + (pt >> 7) * 3;
          p0 = vv[0]; p1 = vv[1]; p2 = vv[2];
        }
        v += p0 * w0q + p1 * w1q + p2 * w2q;
      }
      acc[ptc][ct] = v;
    }
  }
  __builtin_amdgcn_s_setprio(1);
#pragma unroll
  for (int ks = 0; ks < NKS; ++ks) {
    f16x8 afr[nCT];
#pragma unroll
    for (int ct = 0; ct < nCT; ++ct)
      afr[ct] = *(const f16x8*)(img + ((((cg * nCT + ct) * NKS + ks) * 64 + lane) << 4));
#pragma unroll
    for (int ptc = 0; ptc < 4; ++ptc) {
      const int pt = pg * 64 + ptc * 16 + col;
      const f16x8 bfr = *(const f16x8*)(L + LDS_ACT + pt * 256 + swz(pt, ks * 64 + kg * 16));
#pragma unroll
      for (int ct = 0; ct < nCT; ++ct)
        acc[ptc][ct] = __builtin_amdgcn_mfma_f32_16x16x32_f16(afr[ct], bfr,
                                                              acc[ptc][ct], 0, 0, 0);
    }
  }
  __builtin_amdgcn_s_setprio(0);
  __syncthreads();  // all act reads done block-wide -> in-place act write safe
#pragma unroll
  for (int ptc = 0; ptc < 4; ++ptc) {
    const int pt = pg * 64 + ptc * 16 + col;
#pragma unroll
    for (int ct = 0; ct < nCT; ++ct) {
      const int ochB = (cg * nCT + ct) * 16 + ochQ;
      const f32x4 v = acc[ptc][ct];
      f16x4 h;
#pragma unroll
      for (int e = 0; e < 4; ++e) h[e] = (f16)fmaxf(v[e], 0.f);
      *(f16x4*)(L + LDS_ACT + pt * 256 + swz(pt, ochB * 2)) = h;
    }
  }
}

// ---------------------------------------------------------------------------
// Main: EXACT R6 shell — 256 pts/block, 512 threads = 8 waves (4 pg x 2 cg),
// grid 1024, __launch_bounds__(512, 2), same LDS size — only the weight
// source changed (global fragment images; dmaW deleted).
// ---------------------------------------------------------------------------
__global__ __launch_bounds__(512, 2) void nerf_main(
    const float* __restrict__ pos, const float* __restrict__ view,
    const char* __restrict__ ws, float* __restrict__ out) {
  __shared__ __align__(16) char L[LDS_SIZE];
  const int t = threadIdx.x, lane = t & 63, w = t >> 6;
  const int pg = w >> 1, cg = w & 1;
  const int base = blockIdx.x * 256;   // 256 points per block
  const float* P = (const float*)(L + LDS_PRM);

  // stage params / pos / view into LDS (as in R6)
  for (int i = t; i < 2560; i += 512)
    ((float*)(L + LDS_PRM))[i] = ((const float*)(ws + WS_PARAMS))[i];
  for (int i = t; i < 768; i += 512)
    ((float*)(L + LDS_POS))[i] = pos[base * 3 + i];
  if (t < 6) ((float*)(L + LDS_VIEW))[t] = view[(base >> 7) * 3 + t];
  __syncthreads();

  // ---- L0 (K=3, pure VALU): h0 = relu(pos @ W0p + b0f) ----
  {
    const int pt = t >> 1, half = t & 1;
    const float* pp = (const float*)(L + LDS_POS) + pt * 3;
    const float p0 = pp[0], p1 = pp[1], p2 = pp[2];
#pragma unroll
    for (int c8 = 0; c8 < 8; ++c8) {
      f16x8 hv;
#pragma unroll
      for (int e = 0; e < 8; ++e) {
        const int ch = half * 64 + c8 * 8 + e;
        const float v = P[ch] + p0 * P[128 + ch] + p1 * P[256 + ch] + p2 * P[384 + ch];
        hv[e] = (f16)fmaxf(v, 0.0f);
      }
      const int kb = half * 64 + c8 * 8;
      *(f16x8*)(L + LDS_ACT + pt * 256 + swz(pt, 2 * kb)) = hv;
    }
  }
  __syncthreads();

  // ---- MFMA layers (weights streamed from global fragment images) ----
  layerF<128,128,0>(L, 1024, ws +      0, pg, cg, lane);  __syncthreads();  // L1
  layerF<128,128,0>(L, 1152, ws +  32768, pg, cg, lane);  __syncthreads();  // L2
  layerF<128,128,0>(L, 1280, ws +  65536, pg, cg, lane);  __syncthreads();  // L3
  layerF<128,128,0>(L, 1408, ws +  98304, pg, cg, lane);  __syncthreads();  // L4
  layerF<128,128,1>(L,  512, ws + 131072, pg, cg, lane);  __syncthreads();  // L5 (skip)
  layerF<128,128,0>(L, 1536, ws + 163840, pg, cg, lane);  __syncthreads();  // L6
  layerF<128,128,0>(L, 1664, ws + 196608, pg, cg, lane);  __syncthreads();  // L7

  // ---- sigma = h7 @ sW + sb, all 512 threads (2 per point), as in R6 ----
  {
    const int pt2 = t >> 1, half = t & 1;
    float s = 0.f;
#pragma unroll
    for (int i8 = 0; i8 < 8; ++i8) {
      const f16x8 h = *(const f16x8*)(L + LDS_ACT + pt2 * 256 + swz(pt2, half * 128 + i8 * 16));
#pragma unroll
      for (int e = 0; e < 8; ++e) s += (float)h[e] * P[2176 + half * 64 + i8 * 8 + e];
    }
    s += __shfl_xor(s, 1);
    if (!half) ((float*)(L + LDS_SIG))[pt2] = s + P[2304];
  }

  layerF<128,64,2>(L, 1792, ws + 229376, pg, cg, lane);   __syncthreads();  // C0
  layerF<64,64,0>(L, 2048, ws + 245760, pg, cg, lane);    __syncthreads();  // C1
  layerF<64,64,0>(L, 2112, ws + 253952, pg, cg, lane);    __syncthreads();  // C2

  // ---- rgb = hC2 @ rW + rb, 2 threads/point, as in R6 ----
  {
    const int pt2 = t >> 1, half = t & 1;
    float a0 = 0.f, a1 = 0.f, a2 = 0.f;
#pragma unroll
    for (int i8 = 0; i8 < 4; ++i8) {
      const f16x8 h = *(const f16x8*)(L + LDS_ACT + pt2 * 256 + swz(pt2, half * 64 + i8 * 16));
#pragma unroll
      for (int e = 0; e < 8; ++e) {
        const float hv = (float)h[e];
        const int k = half * 32 + i8 * 8 + e;
        a0 += hv * P[2305 + k * 3 + 0];
        a1 += hv * P[2305 + k * 3 + 1];
        a2 += hv * P[2305 + k * 3 + 2];
      }
    }
    a0 += __shfl_xor(a0, 1);
    a1 += __shfl_xor(a1, 1);
    a2 += __shfl_xor(a2, 1);
    if (!half) {
      float4 o;
      o.x = a0 + P[2497]; o.y = a1 + P[2498]; o.z = a2 + P[2499];
      o.w = ((const float*)(L + LDS_SIG))[pt2];
      *(float4*)(out + (base + pt2) * 4) = o;
    }
  }
}

extern "C" void kernel_launch(void* const* d_in, const int* in_sizes, int n_in,
                              void* d_out, int out_size, void* d_ws, size_t ws_size,
                              hipStream_t stream) {
  Ptrs ptrs;
  for (int i = 0; i < 29; ++i) ptrs.p[i] = (const float*)d_in[i];
  char* ws = (char*)d_ws;
  nerf_prep<<<513, 256, 0, stream>>>(ptrs, ws);
  nerf_main<<<1024, 512, 0, stream>>>((const float*)d_in[0], (const float*)d_in[2],
                                      ws, (float*)d_out);
}

// Round 10
// 112.773 us; speedup vs baseline: 1.0021x; 1.0021x over previous
//
#include <hip/hip_runtime.h>

typedef _Float16 f16;
typedef _Float16 f16x8 __attribute__((ext_vector_type(8)));
typedef _Float16 f16x4 __attribute__((ext_vector_type(4)));
typedef float f32x4 __attribute__((ext_vector_type(4)));

// ---------------- d_ws layout ----------------
// [0, 262144) : f16 weight images, per-lane MFMA A-fragment order:
//   elem (T,ks,lane,j): value = W[k = ks*32+(lane>>4)*8+j][ch = T*16+(lane&15)]
//   at imgbase + ((T*nks + ks)*64 + lane)*16 + j*2
//   L1..L7 (128x128, nks=4, 8 T): i*32768, i=0..6   (L5 uses dW5 rows 67..194)
//   C0h    (128x64,  nks=4, 4 T): 229376, 16384 B   (cW0 rows 0..127)
//   C1     (64x64,   nks=2, 4 T): 245760, 8192 B
//   C2     (64x64,   nks=2, 4 T): 253952, 8192 B
// [262144, +10240) : fp32 params block (R1/R4/R6 layout):
//   0 b0f[128] | 128 W0p[3][128] | 512 b5f[128] | 640 W5p[3][128]
//   1024 db1 1152 db2 1280 db3 1408 db4 1536 db6 1664 db7 (x128)
//   1792 cb0[64] | 1856 cWv[3][64] | 2048 cb1[64] | 2112 cb2[64]
//   2176 sW[128] | 2304 sb | 2305 rW[64][3] | 2497 rb[3]
#define WS_PARAMS 262144

// ---------------- LDS layout (bytes) — R9 compacted (dead W0/W1 removed) ----
// act 64KB | params 10KB | pos 3KB | view 24B | sig 1KB => 79,896 B
// => 2 blocks/CU (was 1 at 145KB). Everything else identical to passing R9.
#define LDS_ACT   0
#define LDS_PRM   65536
#define LDS_POS   75776
#define LDS_VIEW  78848
#define LDS_SIG   78872
#define LDS_SIZE  79896

__device__ __forceinline__ int swz(int row, int byteInRow) {
  return byteInRow ^ ((row & 7) << 4);
}

struct Ptrs { const float* p[29]; };

// ---------------------------------------------------------------------------
// Prepass: params block verbatim from validated R4/R6; weight-fragment
// packing verbatim from R2/R9 (validated at absmax 2.44e-4).
// ---------------------------------------------------------------------------
__global__ void nerf_prep(Ptrs ptrs, char* __restrict__ ws) {
  const int t = threadIdx.x;
  if (blockIdx.x == 0) {
    float* P = (float*)(ws + WS_PARAMS);
    const float* cond = ptrs.p[1];
    const float* dW0 = ptrs.p[3];  const float* db0 = ptrs.p[4];
    const float* dW5 = ptrs.p[13]; const float* db5 = ptrs.p[14];
    if (t < 128) {
      float a0 = db0[t], a5 = db5[t];
      for (int k = 0; k < 64; ++k) {
        const float c = cond[k];
        a0 += c * dW0[(3 + k) * 128 + t];
        a5 += c * dW5[(3 + k) * 128 + t];
      }
      P[t] = a0;          // b0f
      P[512 + t] = a5;    // b5f
      for (int k = 0; k < 3; ++k) {
        P[128 + k * 128 + t] = dW0[k * 128 + t];   // W0p
        P[640 + k * 128 + t] = dW5[k * 128 + t];   // W5p
      }
      P[1024 + t] = ptrs.p[6][t];    // db1
      P[1152 + t] = ptrs.p[8][t];    // db2
      P[1280 + t] = ptrs.p[10][t];   // db3
      P[1408 + t] = ptrs.p[12][t];   // db4
      P[1536 + t] = ptrs.p[16][t];   // db6
      P[1664 + t] = ptrs.p[18][t];   // db7
      P[2176 + t] = ptrs.p[19][t];   // sW
    }
    if (t < 64) {
      P[1792 + t] = ptrs.p[22][t];   // cb0
      for (int k = 0; k < 3; ++k)    // cWv = cW0 rows 128..130
        P[1856 + k * 64 + t] = ptrs.p[21][(128 + k) * 64 + t];
      P[2048 + t] = ptrs.p[24][t];   // cb1
      P[2112 + t] = ptrs.p[26][t];   // cb2
    }
    if (t < 192) P[2305 + t] = ptrs.p[27][t];  // rW [64][3]
    if (t == 0) {
      P[2304] = ptrs.p[20][0];                 // sb
      P[2497] = ptrs.p[28][0];
      P[2498] = ptrs.p[28][1];
      P[2499] = ptrs.p[28][2];                 // rb
    }
    return;
  }
  // 131072 f16 weight-fragment elements across blocks 1..512 (R2 formulas)
  const int e = (blockIdx.x - 1) * 256 + t;
  float v; int dst;
  if (e < 114688) {                       // L1..L7
    const int img = e >> 14, o = e & 16383;
    const int j = o & 7, lane = (o >> 3) & 63, ks = (o >> 9) & 3, T = o >> 11;
    const int k = ks * 32 + ((lane >> 4) << 3) + j, ch = T * 16 + (lane & 15);
    v = ptrs.p[5 + 2 * img][(k + (img == 4 ? 67 : 0)) * 128 + ch];
    dst = img * 32768 + (((T * 4 + ks) * 64 + lane) << 4) + (j << 1);
  } else if (e < 122880) {                // C0h
    const int o = e - 114688;
    const int j = o & 7, lane = (o >> 3) & 63, ks = (o >> 9) & 3, T = o >> 11;
    const int k = ks * 32 + ((lane >> 4) << 3) + j, ch = T * 16 + (lane & 15);
    v = ptrs.p[21][k * 64 + ch];
    dst = 229376 + (((T * 4 + ks) * 64 + lane) << 4) + (j << 1);
  } else if (e < 126976) {                // C1
    const int o = e - 122880;
    const int j = o & 7, lane = (o >> 3) & 63, ks = (o >> 9) & 1, T = o >> 10;
    const int k = ks * 32 + ((lane >> 4) << 3) + j, ch = T * 16 + (lane & 15);
    v = ptrs.p[23][k * 64 + ch];
    dst = 245760 + (((T * 2 + ks) * 64 + lane) << 4) + (j << 1);
  } else {                                // C2
    const int o = e - 126976;
    const int j = o & 7, lane = (o >> 3) & 63, ks = (o >> 9) & 1, T = o >> 10;
    const int k = ks * 32 + ((lane >> 4) << 3) + j, ch = T * 16 + (lane & 15);
    v = ptrs.p[25][k * 64 + ch];
    dst = 253952 + (((T * 2 + ks) * 64 + lane) << 4) + (j << 1);
  }
  *(f16*)(ws + dst) = (f16)v;
}

// ---------------------------------------------------------------------------
// layerF: verbatim from passing R9 — A per-ks from global fragment image,
// B from LDS act; C row=och, col=pt; packed f16x4 epilogue.
// INIT: 0 = bias only, 1 = bias + pos*W5p, 2 = bias + view*cWv
// ---------------------------------------------------------------------------
template<int K, int N, int INIT>
__device__ __forceinline__ void layerF(char* L, int biasOff,
                                       const char* __restrict__ img,
                                       int pg, int cg, int lane) {
  const float* P = (const float*)(L + LDS_PRM);
  const int col = lane & 15, kg = lane >> 4;
  constexpr int nCT = (N == 128) ? 4 : 2;
  constexpr int NKS = K / 32;
  const int ochQ = kg * 4;
  f32x4 acc[4][nCT];
#pragma unroll
  for (int ct = 0; ct < nCT; ++ct) {
    const int ochB = (cg * nCT + ct) * 16 + ochQ;
    const f32x4 bq = *(const f32x4*)(P + biasOff + ochB);
    f32x4 w0q, w1q, w2q;
    if (INIT == 1) {
      w0q = *(const f32x4*)(P + 640 + ochB);
      w1q = *(const f32x4*)(P + 768 + ochB);
      w2q = *(const f32x4*)(P + 896 + ochB);
    } else if (INIT == 2) {
      w0q = *(const f32x4*)(P + 1856 + ochB);
      w1q = *(const f32x4*)(P + 1920 + ochB);
      w2q = *(const f32x4*)(P + 1984 + ochB);
    }
#pragma unroll
    for (int ptc = 0; ptc < 4; ++ptc) {
      f32x4 v = bq;
      if (INIT != 0) {
        const int pt = pg * 64 + ptc * 16 + col;
        float p0, p1, p2;
        if (INIT == 1) {
          const float* pp = (const float*)(L + LDS_POS) + pt * 3;
          p0 = pp[0]; p1 = pp[1]; p2 = pp[2];
        } else {
          const float* vv = (const float*)(L + LDS_VIEW) + (pt >> 7) * 3;
          p0 = vv[0]; p1 = vv[1]; p2 = vv[2];
        }
        v += p0 * w0q + p1 * w1q + p2 * w2q;
      }
      acc[ptc][ct] = v;
    }
  }
  __builtin_amdgcn_s_setprio(1);
#pragma unroll
  for (int ks = 0; ks < NKS; ++ks) {
    f16x8 afr[nCT];
#pragma unroll
    for (int ct = 0; ct < nCT; ++ct)
      afr[ct] = *(const f16x8*)(img + ((((cg * nCT + ct) * NKS + ks) * 64 + lane) << 4));
#pragma unroll
    for (int ptc = 0; ptc < 4; ++ptc) {
      const int pt = pg * 64 + ptc * 16 + col;
      const f16x8 bfr = *(const f16x8*)(L + LDS_ACT + pt * 256 + swz(pt, ks * 64 + kg * 16));
#pragma unroll
      for (int ct = 0; ct < nCT; ++ct)
        acc[ptc][ct] = __builtin_amdgcn_mfma_f32_16x16x32_f16(afr[ct], bfr,
                                                              acc[ptc][ct], 0, 0, 0);
    }
  }
  __builtin_amdgcn_s_setprio(0);
  __syncthreads();  // all act reads done block-wide -> in-place act write safe
#pragma unroll
  for (int ptc = 0; ptc < 4; ++ptc) {
    const int pt = pg * 64 + ptc * 16 + col;
#pragma unroll
    for (int ct = 0; ct < nCT; ++ct) {
      const int ochB = (cg * nCT + ct) * 16 + ochQ;
      const f32x4 v = acc[ptc][ct];
      f16x4 h;
#pragma unroll
      for (int e = 0; e < 4; ++e) h[e] = (f16)fmaxf(v[e], 0.f);
      *(f16x4*)(L + LDS_ACT + pt * 256 + swz(pt, ochB * 2)) = h;
    }
  }
}

// ---------------------------------------------------------------------------
// Main: blessed shell — 256 pts/block, 512 threads = 8 waves (4 pg x 2 cg),
// grid 1024, __launch_bounds__(512, 2). Only change vs R9: compact LDS
// (79,896 B) => 2 blocks/CU.
// ---------------------------------------------------------------------------
__global__ __launch_bounds__(512, 2) void nerf_main(
    const float* __restrict__ pos, const float* __restrict__ view,
    const char* __restrict__ ws, float* __restrict__ out) {
  __shared__ __align__(16) char L[LDS_SIZE];
  const int t = threadIdx.x, lane = t & 63, w = t >> 6;
  const int pg = w >> 1, cg = w & 1;
  const int base = blockIdx.x * 256;   // 256 points per block
  const float* P = (const float*)(L + LDS_PRM);

  // stage params / pos / view into LDS
  for (int i = t; i < 2560; i += 512)
    ((float*)(L + LDS_PRM))[i] = ((const float*)(ws + WS_PARAMS))[i];
  for (int i = t; i < 768; i += 512)
    ((float*)(L + LDS_POS))[i] = pos[base * 3 + i];
  if (t < 6) ((float*)(L + LDS_VIEW))[t] = view[(base >> 7) * 3 + t];
  __syncthreads();

  // ---- L0 (K=3, pure VALU): h0 = relu(pos @ W0p + b0f) ----
  {
    const int pt = t >> 1, half = t & 1;
    const float* pp = (const float*)(L + LDS_POS) + pt * 3;
    const float p0 = pp[0], p1 = pp[1], p2 = pp[2];
#pragma unroll
    for (int c8 = 0; c8 < 8; ++c8) {
      f16x8 hv;
#pragma unroll
      for (int e = 0; e < 8; ++e) {
        const int ch = half * 64 + c8 * 8 + e;
        const float v = P[ch] + p0 * P[128 + ch] + p1 * P[256 + ch] + p2 * P[384 + ch];
        hv[e] = (f16)fmaxf(v, 0.0f);
      }
      const int kb = half * 64 + c8 * 8;
      *(f16x8*)(L + LDS_ACT + pt * 256 + swz(pt, 2 * kb)) = hv;
    }
  }
  __syncthreads();

  // ---- MFMA layers (weights streamed from global fragment images) ----
  layerF<128,128,0>(L, 1024, ws +      0, pg, cg, lane);  __syncthreads();  // L1
  layerF<128,128,0>(L, 1152, ws +  32768, pg, cg, lane);  __syncthreads();  // L2
  layerF<128,128,0>(L, 1280, ws +  65536, pg, cg, lane);  __syncthreads();  // L3
  layerF<128,128,0>(L, 1408, ws +  98304, pg, cg, lane);  __syncthreads();  // L4
  layerF<128,128,1>(L,  512, ws + 131072, pg, cg, lane);  __syncthreads();  // L5 (skip)
  layerF<128,128,0>(L, 1536, ws + 163840, pg, cg, lane);  __syncthreads();  // L6
  layerF<128,128,0>(L, 1664, ws + 196608, pg, cg, lane);  __syncthreads();  // L7

  // ---- sigma = h7 @ sW + sb, all 512 threads (2 per point) ----
  {
    const int pt2 = t >> 1, half = t & 1;
    float s = 0.f;
#pragma unroll
    for (int i8 = 0; i8 < 8; ++i8) {
      const f16x8 h = *(const f16x8*)(L + LDS_ACT + pt2 * 256 + swz(pt2, half * 128 + i8 * 16));
#pragma unroll
      for (int e = 0; e < 8; ++e) s += (float)h[e] * P[2176 + half * 64 + i8 * 8 + e];
    }
    s += __shfl_xor(s, 1);
    if (!half) ((float*)(L + LDS_SIG))[pt2] = s + P[2304];
  }

  layerF<128,64,2>(L, 1792, ws + 229376, pg, cg, lane);   __syncthreads();  // C0
  layerF<64,64,0>(L, 2048, ws + 245760, pg, cg, lane);    __syncthreads();  // C1
  layerF<64,64,0>(L, 2112, ws + 253952, pg, cg, lane);    __syncthreads();  // C2

  // ---- rgb = hC2 @ rW + rb, 2 threads/point ----
  {
    const int pt2 = t >> 1, half = t & 1;
    float a0 = 0.f, a1 = 0.f, a2 = 0.f;
#pragma unroll
    for (int i8 = 0; i8 < 4; ++i8) {
      const f16x8 h = *(const f16x8*)(L + LDS_ACT + pt2 * 256 + swz(pt2, half * 64 + i8 * 16));
#pragma unroll
      for (int e = 0; e < 8; ++e) {
        const float hv = (float)h[e];
        const int k = half * 32 + i8 * 8 + e;
        a0 += hv * P[2305 + k * 3 + 0];
        a1 += hv * P[2305 + k * 3 + 1];
        a2 += hv * P[2305 + k * 3 + 2];
      }
    }
    a0 += __shfl_xor(a0, 1);
    a1 += __shfl_xor(a1, 1);
    a2 += __shfl_xor(a2, 1);
    if (!half) {
      float4 o;
      o.x = a0 + P[2497]; o.y = a1 + P[2498]; o.z = a2 + P[2499];
      o.w = ((const float*)(L + LDS_SIG))[pt2];
      *(float4*)(out + (base + pt2) * 4) = o;
    }
  }
}

extern "C" void kernel_launch(void* const* d_in, const int* in_sizes, int n_in,
                              void* d_out, int out_size, void* d_ws, size_t ws_size,
                              hipStream_t stream) {
  Ptrs ptrs;
  for (int i = 0; i < 29; ++i) ptrs.p[i] = (const float*)d_in[i];
  char* ws = (char*)d_ws;
  nerf_prep<<<513, 256, 0, stream>>>(ptrs, ws);
  nerf_main<<<1024, 512, 0, stream>>>((const float*)d_in[0], (const float*)d_in[2],
                                      ws, (float*)d_out);
}